// Round 1
// baseline (728.529 us; speedup 1.0000x reference)
//
#include <hip/hip_runtime.h>

#define NN 100000
#define NE 3200000
#define DD 128

typedef float f4 __attribute__((ext_vector_type(4)));

// ---------------- CSR build ----------------

__global__ void k_zero_i32(int* __restrict__ p, int n) {
  int i = blockIdx.x * 256 + threadIdx.x;
  if (i < n) p[i] = 0;
}

__global__ void k_hist(const int* __restrict__ row, int* __restrict__ cnt) {
  int e = blockIdx.x * 256 + threadIdx.x;
  if (e < NE) atomicAdd(&cnt[row[e]], 1);
}

// per-block (1024 elems) exclusive scan + block sums
__global__ __launch_bounds__(256) void k_scan1(const int* __restrict__ in,
                                               int* __restrict__ out,
                                               int* __restrict__ bsum, int n) {
  __shared__ int sh[256];
  const int t = threadIdx.x;
  const int base = blockIdx.x * 1024 + t * 4;
  int v0 = (base + 0 < n) ? in[base + 0] : 0;
  int v1 = (base + 1 < n) ? in[base + 1] : 0;
  int v2 = (base + 2 < n) ? in[base + 2] : 0;
  int v3 = (base + 3 < n) ? in[base + 3] : 0;
  int s0 = v0, s1 = s0 + v1, s2 = s1 + v2, s3 = s2 + v3;
  sh[t] = s3;
  __syncthreads();
  for (int off = 1; off < 256; off <<= 1) {
    int x = (t >= off) ? sh[t - off] : 0;
    __syncthreads();
    sh[t] += x;
    __syncthreads();
  }
  int excl = (t > 0) ? sh[t - 1] : 0;
  if (base + 0 < n) out[base + 0] = excl;
  if (base + 1 < n) out[base + 1] = excl + s0;
  if (base + 2 < n) out[base + 2] = excl + s1;
  if (base + 3 < n) out[base + 3] = excl + s2;
  if (t == 255) bsum[blockIdx.x] = sh[255];
}

__global__ void k_scan2(int* __restrict__ b, int nb) {
  __shared__ int sh[128];
  int t = threadIdx.x;
  sh[t] = (t < nb) ? b[t] : 0;
  __syncthreads();
  for (int off = 1; off < 128; off <<= 1) {
    int x = (t >= off) ? sh[t - off] : 0;
    __syncthreads();
    sh[t] += x;
    __syncthreads();
  }
  if (t < nb) b[t] = (t > 0) ? sh[t - 1] : 0;
}

__global__ void k_scan3(int* __restrict__ rp, const int* __restrict__ bsum,
                        int* __restrict__ cur, int n) {
  int i = blockIdx.x * 256 + threadIdx.x;
  if (i < n) {
    int v = rp[i] + bsum[i >> 10];
    rp[i] = v;
    cur[i] = v;
  }
  if (i == 0) rp[n] = NE;
}

__global__ void k_scatter(const int* __restrict__ row, const int* __restrict__ col,
                          const float* __restrict__ val, int* __restrict__ cur,
                          int* __restrict__ cs, float* __restrict__ vs) {
  int e = blockIdx.x * 256 + threadIdx.x;
  if (e < NE) {
    int r = row[e];
    int p = atomicAdd(&cur[r], 1);
    cs[p] = col[e];
    vs[p] = val[e];
  }
}

// ---------------- weight prep: Bmat[k][j] = (k<128 ? Wp[j][k] : Ws[j][k-128]) ----------------

__global__ void k_transW(const float* __restrict__ Wp, const float* __restrict__ Ws,
                         const float* __restrict__ bp, const float* __restrict__ bs,
                         float* __restrict__ Bmat, float* __restrict__ bias) {
  int idx = blockIdx.x * 256 + threadIdx.x;
  if (idx < 2 * DD * DD) {
    int k = idx >> 7, j = idx & 127;
    Bmat[idx] = (k < DD) ? Wp[j * DD + k] : Ws[j * DD + (k - DD)];
  }
  if (idx < DD) bias[idx] = bp[idx] + bs[idx];
}

// ---------------- SpMM: wave per node, lane holds float2 of the 128-wide row ----------------

__global__ __launch_bounds__(256) void k_spmm(const int* __restrict__ rp,
                                              const int* __restrict__ cs,
                                              const float* __restrict__ vs,
                                              const float* __restrict__ X,
                                              float* __restrict__ agg) {
  const int w = threadIdx.x >> 6;
  const int lane = threadIdx.x & 63;
  const int node = blockIdx.x * 4 + w;
  int beg = rp[node], end = rp[node + 1];
  beg = __builtin_amdgcn_readfirstlane(beg);
  end = __builtin_amdgcn_readfirstlane(end);
  const float2* __restrict__ Xv = (const float2*)X;
  float ax = 0.f, ay = 0.f;
  int e = beg;
  for (; e + 4 <= end; e += 4) {
    int c0 = cs[e], c1 = cs[e + 1], c2 = cs[e + 2], c3 = cs[e + 3];
    float v0 = vs[e], v1 = vs[e + 1], v2 = vs[e + 2], v3 = vs[e + 3];
    float2 x0 = Xv[c0 * 64 + lane];
    float2 x1 = Xv[c1 * 64 + lane];
    float2 x2 = Xv[c2 * 64 + lane];
    float2 x3 = Xv[c3 * 64 + lane];
    ax += v0 * x0.x; ay += v0 * x0.y;
    ax += v1 * x1.x; ay += v1 * x1.y;
    ax += v2 * x2.x; ay += v2 * x2.y;
    ax += v3 * x3.x; ay += v3 * x3.y;
  }
  for (; e < end; e++) {
    int c = cs[e];
    float v = vs[e];
    float2 x = Xv[c * 64 + lane];
    ax += v * x.x; ay += v * x.y;
  }
  float2 o; o.x = ax; o.y = ay;
  ((float2*)agg)[node * 64 + lane] = o;
}

// ---------------- fused GEMM: out = [agg|X] @ Bmat + bias   (M=100k, K=256, N=128) ----------------
// agg aliases out: each block reads only its own 64 rows during the K loop,
// then overwrites exactly those rows in the epilogue -> safe.

__global__ __launch_bounds__(256) void k_gemm(const float* __restrict__ Aagg,
                                              const float* __restrict__ X,
                                              const float* __restrict__ Bmat,
                                              const float* __restrict__ bias,
                                              float* __restrict__ out) {
  __shared__ float As[16][68];    // transposed A tile, padded: stride 272B = 17*16
  __shared__ float Bs[16][132];   // stride 528B = 33*16

  const int t = threadIdx.x;
  const int i0 = blockIdx.x * 64;
  const int tm = t >> 4;   // 0..15 -> rows tm*4..tm*4+3
  const int tn = t & 15;   // 0..15 -> cols tn*4..+3 and 64+tn*4..+3

  float acc[4][8];
#pragma unroll
  for (int r = 0; r < 4; r++)
#pragma unroll
    for (int c = 0; c < 8; c++) acc[r][c] = 0.f;

  const int sr = t >> 2;          // A staging row 0..63
  const int sc = (t & 3) * 4;     // A staging col 0,4,8,12
  int arow = i0 + sr;
  if (arow >= NN) arow = NN - 1;  // clamp (last block only; stays within this block's rows)
  const int brow = t >> 4;        // B staging row 0..15
  const int bcol = (t & 15) * 8;  // B staging col

  for (int kb = 0; kb < 256; kb += 16) {
    const float* __restrict__ asrc = (kb < 128) ? (Aagg + (size_t)arow * 128 + kb)
                                                : (X + (size_t)arow * 128 + (kb - 128));
    f4 av = *(const f4*)(asrc + sc);
    f4 bv0 = *(const f4*)&Bmat[(kb + brow) * 128 + bcol];
    f4 bv1 = *(const f4*)&Bmat[(kb + brow) * 128 + bcol + 4];
    __syncthreads();  // previous iteration's LDS reads done
    As[sc + 0][sr] = av[0];
    As[sc + 1][sr] = av[1];
    As[sc + 2][sr] = av[2];
    As[sc + 3][sr] = av[3];
    *(f4*)&Bs[brow][bcol] = bv0;
    *(f4*)&Bs[brow][bcol + 4] = bv1;
    __syncthreads();
#pragma unroll
    for (int kk = 0; kk < 16; kk++) {
      f4 a = *(const f4*)&As[kk][tm * 4];
      f4 b0 = *(const f4*)&Bs[kk][tn * 4];
      f4 b1 = *(const f4*)&Bs[kk][64 + tn * 4];
#pragma unroll
      for (int r = 0; r < 4; r++) {
#pragma unroll
        for (int c = 0; c < 4; c++) {
          acc[r][c] += a[r] * b0[c];
          acc[r][c + 4] += a[r] * b1[c];
        }
      }
    }
  }

  f4 bb0 = *(const f4*)&bias[tn * 4];
  f4 bb1 = *(const f4*)&bias[64 + tn * 4];
#pragma unroll
  for (int r = 0; r < 4; r++) {
    int i = i0 + tm * 4 + r;
    if (i < NN) {
      f4 o0, o1;
#pragma unroll
      for (int c = 0; c < 4; c++) {
        o0[c] = acc[r][c] + bb0[c];
        o1[c] = acc[r][c + 4] + bb1[c];
      }
      *(f4*)&out[(size_t)i * 128 + tn * 4] = o0;
      *(f4*)&out[(size_t)i * 128 + 64 + tn * 4] = o1;
    }
  }
}

// ---------------- launch ----------------

extern "C" void kernel_launch(void* const* d_in, const int* in_sizes, int n_in,
                              void* d_out, int out_size, void* d_ws, size_t ws_size,
                              hipStream_t stream) {
  (void)in_sizes; (void)n_in; (void)out_size; (void)ws_size;
  const int*   erow = (const int*)d_in[0];
  const int*   ecol = (const int*)d_in[1];
  const float* eval = (const float*)d_in[2];
  const float* X    = (const float*)d_in[3];
  const float* Wp   = (const float*)d_in[4];
  const float* bp   = (const float*)d_in[5];
  const float* Ws   = (const float*)d_in[6];
  const float* bs   = (const float*)d_in[7];
  float* out = (float*)d_out;

  char* ws = (char*)d_ws;
  size_t off = 0;
  auto alloc = [&](size_t bytes) -> void* {
    void* p = ws + off;
    off = (off + bytes + 255) & ~(size_t)255;
    return p;
  };
  int*   cnt  = (int*)alloc((size_t)NN * 4);
  int*   rp   = (int*)alloc((size_t)(NN + 1) * 4);
  int*   cur  = (int*)alloc((size_t)NN * 4);
  int*   bsum = (int*)alloc(128 * 4);
  int*   cs   = (int*)alloc((size_t)NE * 4);
  float* vs   = (float*)alloc((size_t)NE * 4);
  float* Bmat = (float*)alloc((size_t)2 * DD * DD * 4);
  float* bias = (float*)alloc(DD * 4);

  hipLaunchKernelGGL(k_zero_i32, dim3((NN + 255) / 256), dim3(256), 0, stream, cnt, NN);
  hipLaunchKernelGGL(k_hist, dim3((NE + 255) / 256), dim3(256), 0, stream, erow, cnt);
  hipLaunchKernelGGL(k_scan1, dim3(98), dim3(256), 0, stream, cnt, rp, bsum, NN);
  hipLaunchKernelGGL(k_scan2, dim3(1), dim3(128), 0, stream, bsum, 98);
  hipLaunchKernelGGL(k_scan3, dim3((NN + 255) / 256), dim3(256), 0, stream, rp, bsum, cur, NN);
  hipLaunchKernelGGL(k_scatter, dim3((NE + 255) / 256), dim3(256), 0, stream, erow, ecol, eval, cur, cs, vs);
  hipLaunchKernelGGL(k_transW, dim3(128), dim3(256), 0, stream, Wp, Ws, bp, bs, Bmat, bias);
  hipLaunchKernelGGL(k_spmm, dim3(NN / 4), dim3(256), 0, stream, rp, cs, vs, X, out);
  hipLaunchKernelGGL(k_gemm, dim3((NN + 63) / 64), dim3(256), 0, stream, out, X, Bmat, bias, out);
}

// Round 2
// 424.780 us; speedup vs baseline: 1.7151x; 1.7151x over previous
//
#include <hip/hip_runtime.h>

#define NN 100000
#define NE 3200000
#define DD 128
#define NBUCK 391        // ceil(NN / 256) row-buckets of 256 rows
#define P1_EDGES 12288   // edges per k_bin block
#define P2_CAP 12288     // LDS staging capacity in k_bsort (avg bucket = 8192)

typedef float f4 __attribute__((ext_vector_type(4)));
typedef unsigned long long u64;

// ---------------- bucket histogram (LDS-aggregated) ----------------

__global__ void k_zero_small(int* __restrict__ p, int n) {
  int i = blockIdx.x * 256 + threadIdx.x;
  if (i < n) p[i] = 0;
}

__global__ __launch_bounds__(256) void k_bhist(const int* __restrict__ erow,
                                               int* __restrict__ bcount) {
  __shared__ int cnt[NBUCK];
  for (int i = threadIdx.x; i < NBUCK; i += 256) cnt[i] = 0;
  __syncthreads();
  const long long tid = (long long)blockIdx.x * 256 + threadIdx.x;
  const long long stride = (long long)gridDim.x * 256;
  for (long long e = tid; e < NE; e += stride) atomicAdd(&cnt[erow[e] >> 8], 1);
  __syncthreads();
  for (int i = threadIdx.x; i < NBUCK; i += 256)
    if (cnt[i]) atomicAdd(&bcount[i], cnt[i]);
}

// single-block exclusive scan over 391 bucket counts
__global__ __launch_bounds__(512) void k_bscan(const int* __restrict__ bcount,
                                               int* __restrict__ bbase,
                                               int* __restrict__ gcur) {
  __shared__ int sh[512];
  const int t = threadIdx.x;
  int v = (t < NBUCK) ? bcount[t] : 0;
  sh[t] = v;
  __syncthreads();
  for (int off = 1; off < 512; off <<= 1) {
    int x = (t >= off) ? sh[t - off] : 0;
    __syncthreads();
    sh[t] += x;
    __syncthreads();
  }
  int excl = (t > 0) ? sh[t - 1] : 0;
  if (t < NBUCK) { bbase[t] = excl; gcur[t] = excl; }
  if (t == NBUCK) bbase[t] = excl;  // == NE
}

// ---------------- pass 1: bin edges into bucket-grouped packed array ----------------
// packed u64: [ rowlocal(8b) << 52 | col(17b) << 32 | f32 val bits ]

__global__ __launch_bounds__(256) void k_bin(const int* __restrict__ erow,
                                             const int* __restrict__ ecol,
                                             const float* __restrict__ eval,
                                             int* __restrict__ gcur,
                                             u64* __restrict__ epk) {
  __shared__ int cnt[NBUCK];
  __shared__ int gbase[NBUCK];
  const int t = threadIdx.x;
  const long long e0 = (long long)blockIdx.x * P1_EDGES;
  long long rem = (long long)NE - e0;
  const int ecnt = (int)(rem < P1_EDGES ? rem : P1_EDGES);
  for (int i = t; i < NBUCK; i += 256) cnt[i] = 0;
  __syncthreads();
  for (int i = t; i < ecnt; i += 256) atomicAdd(&cnt[erow[e0 + i] >> 8], 1);
  __syncthreads();
  for (int i = t; i < NBUCK; i += 256) {
    int c = cnt[i];
    gbase[i] = c ? atomicAdd(&gcur[i], c) : 0;
    cnt[i] = 0;  // reuse as local cursor
  }
  __syncthreads();
  for (int i = t; i < ecnt; i += 256) {
    int r = erow[e0 + i];
    unsigned c = (unsigned)ecol[e0 + i];
    unsigned v = __float_as_uint(eval[e0 + i]);
    int b = r >> 8;
    int p = atomicAdd(&cnt[b], 1);
    u64 pk = ((u64)((((unsigned)(r & 255)) << 20) | c) << 32) | v;
    epk[(long long)gbase[b] + p] = pk;
  }
}

// ---------------- pass 2: per-bucket counting sort (in place) + emit rp ----------------

__global__ __launch_bounds__(256) void k_bsort(const int* __restrict__ bbase,
                                               u64* __restrict__ epk,
                                               int* __restrict__ rp) {
  __shared__ u64 stg[P2_CAP];
  __shared__ int sc[256];
  __shared__ int cur[256];
  const int t = threadIdx.x;
  const int gb = blockIdx.x;
  const int r0 = gb << 8;
  const int rows = (NN - r0 < 256) ? (NN - r0) : 256;
  const int s = bbase[gb];
  const int cnt = bbase[gb + 1] - s;

  cur[t] = 0;
  __syncthreads();
  for (int i = t; i < cnt; i += 256) {
    int rl = (int)((epk[s + i] >> 52) & 255);
    atomicAdd(&cur[rl], 1);
  }
  __syncthreads();
  int c0 = cur[t];
  sc[t] = c0;
  __syncthreads();
  for (int off = 1; off < 256; off <<= 1) {
    int x = (t >= off) ? sc[t - off] : 0;
    __syncthreads();
    sc[t] += x;
    __syncthreads();
  }
  int mybase = sc[t] - c0;  // exclusive scan
  cur[t] = mybase;
  if (t < rows) rp[r0 + t] = s + mybase;
  if (gb == NBUCK - 1 && t == 0) rp[NN] = NE;
  __syncthreads();
  for (int i = t; i < cnt; i += 256) {
    u64 pk = epk[s + i];
    int rl = (int)((pk >> 52) & 255);
    int p = atomicAdd(&cur[rl], 1);
    if (p < P2_CAP) stg[p] = pk;
  }
  __syncthreads();
  for (int i = t; i < cnt; i += 256) epk[s + i] = stg[i];
}

// ---------------- weight prep: Bmat[k][j] = (k<128 ? Wp[j][k] : Ws[j][k-128]) ----------------

__global__ void k_transW(const float* __restrict__ Wp, const float* __restrict__ Ws,
                         const float* __restrict__ bp, const float* __restrict__ bs,
                         float* __restrict__ Bmat, float* __restrict__ bias) {
  int idx = blockIdx.x * 256 + threadIdx.x;
  if (idx < 2 * DD * DD) {
    int k = idx >> 7, j = idx & 127;
    Bmat[idx] = (k < DD) ? Wp[j * DD + k] : Ws[j * DD + (k - DD)];
  }
  if (idx < DD) bias[idx] = bp[idx] + bs[idx];
}

// ---------------- SpMM: wave per node, lane holds float2 of the 128-wide row ----------------

__global__ __launch_bounds__(256) void k_spmm(const int* __restrict__ rp,
                                              const u64* __restrict__ epk,
                                              const float* __restrict__ X,
                                              float* __restrict__ agg) {
  const int w = threadIdx.x >> 6;
  const int lane = threadIdx.x & 63;
  const int node = blockIdx.x * 4 + w;
  int beg = __builtin_amdgcn_readfirstlane(rp[node]);
  int end = __builtin_amdgcn_readfirstlane(rp[node + 1]);
  const float2* __restrict__ Xv = (const float2*)X;
  float ax = 0.f, ay = 0.f;
  int e = beg;
  for (; e + 4 <= end; e += 4) {
    u64 p0 = epk[e], p1 = epk[e + 1], p2 = epk[e + 2], p3 = epk[e + 3];
    int c0 = (int)(p0 >> 32) & 0x1FFFF; float v0 = __uint_as_float((unsigned)p0);
    int c1 = (int)(p1 >> 32) & 0x1FFFF; float v1 = __uint_as_float((unsigned)p1);
    int c2 = (int)(p2 >> 32) & 0x1FFFF; float v2 = __uint_as_float((unsigned)p2);
    int c3 = (int)(p3 >> 32) & 0x1FFFF; float v3 = __uint_as_float((unsigned)p3);
    float2 x0 = Xv[c0 * 64 + lane];
    float2 x1 = Xv[c1 * 64 + lane];
    float2 x2 = Xv[c2 * 64 + lane];
    float2 x3 = Xv[c3 * 64 + lane];
    ax += v0 * x0.x; ay += v0 * x0.y;
    ax += v1 * x1.x; ay += v1 * x1.y;
    ax += v2 * x2.x; ay += v2 * x2.y;
    ax += v3 * x3.x; ay += v3 * x3.y;
  }
  for (; e < end; e++) {
    u64 p0 = epk[e];
    int c = (int)(p0 >> 32) & 0x1FFFF; float v = __uint_as_float((unsigned)p0);
    float2 x = Xv[c * 64 + lane];
    ax += v * x.x; ay += v * x.y;
  }
  float2 o; o.x = ax; o.y = ay;
  ((float2*)agg)[node * 64 + lane] = o;
}

// ---------------- fused GEMM: out = [agg|X] @ Bmat + bias   (M=100k, K=256, N=128) ----------------
// agg aliases out: each block reads only its own 64 rows during the K loop,
// then overwrites exactly those rows in the epilogue -> safe.

__global__ __launch_bounds__(256) void k_gemm(const float* __restrict__ Aagg,
                                              const float* __restrict__ X,
                                              const float* __restrict__ Bmat,
                                              const float* __restrict__ bias,
                                              float* __restrict__ out) {
  __shared__ float As[16][68];
  __shared__ float Bs[16][132];

  const int t = threadIdx.x;
  const int i0 = blockIdx.x * 64;
  const int tm = t >> 4;
  const int tn = t & 15;

  float acc[4][8];
#pragma unroll
  for (int r = 0; r < 4; r++)
#pragma unroll
    for (int c = 0; c < 8; c++) acc[r][c] = 0.f;

  const int sr = t >> 2;
  const int sc = (t & 3) * 4;
  int arow = i0 + sr;
  if (arow >= NN) arow = NN - 1;
  const int brow = t >> 4;
  const int bcol = (t & 15) * 8;

  for (int kb = 0; kb < 256; kb += 16) {
    const float* __restrict__ asrc = (kb < 128) ? (Aagg + (size_t)arow * 128 + kb)
                                                : (X + (size_t)arow * 128 + (kb - 128));
    f4 av = *(const f4*)(asrc + sc);
    f4 bv0 = *(const f4*)&Bmat[(kb + brow) * 128 + bcol];
    f4 bv1 = *(const f4*)&Bmat[(kb + brow) * 128 + bcol + 4];
    __syncthreads();
    As[sc + 0][sr] = av[0];
    As[sc + 1][sr] = av[1];
    As[sc + 2][sr] = av[2];
    As[sc + 3][sr] = av[3];
    *(f4*)&Bs[brow][bcol] = bv0;
    *(f4*)&Bs[brow][bcol + 4] = bv1;
    __syncthreads();
#pragma unroll
    for (int kk = 0; kk < 16; kk++) {
      f4 a = *(const f4*)&As[kk][tm * 4];
      f4 b0 = *(const f4*)&Bs[kk][tn * 4];
      f4 b1 = *(const f4*)&Bs[kk][64 + tn * 4];
#pragma unroll
      for (int r = 0; r < 4; r++) {
#pragma unroll
        for (int c = 0; c < 4; c++) {
          acc[r][c] += a[r] * b0[c];
          acc[r][c + 4] += a[r] * b1[c];
        }
      }
    }
  }

  f4 bb0 = *(const f4*)&bias[tn * 4];
  f4 bb1 = *(const f4*)&bias[64 + tn * 4];
#pragma unroll
  for (int r = 0; r < 4; r++) {
    int i = i0 + tm * 4 + r;
    if (i < NN) {
      f4 o0, o1;
#pragma unroll
      for (int c = 0; c < 4; c++) {
        o0[c] = acc[r][c] + bb0[c];
        o1[c] = acc[r][c + 4] + bb1[c];
      }
      *(f4*)&out[(size_t)i * 128 + tn * 4] = o0;
      *(f4*)&out[(size_t)i * 128 + 64 + tn * 4] = o1;
    }
  }
}

// ---------------- launch ----------------

extern "C" void kernel_launch(void* const* d_in, const int* in_sizes, int n_in,
                              void* d_out, int out_size, void* d_ws, size_t ws_size,
                              hipStream_t stream) {
  (void)in_sizes; (void)n_in; (void)out_size; (void)ws_size;
  const int*   erow = (const int*)d_in[0];
  const int*   ecol = (const int*)d_in[1];
  const float* eval = (const float*)d_in[2];
  const float* X    = (const float*)d_in[3];
  const float* Wp   = (const float*)d_in[4];
  const float* bp   = (const float*)d_in[5];
  const float* Ws   = (const float*)d_in[6];
  const float* bs   = (const float*)d_in[7];
  float* out = (float*)d_out;

  char* ws = (char*)d_ws;
  size_t off = 0;
  auto alloc = [&](size_t bytes) -> void* {
    void* p = ws + off;
    off = (off + bytes + 255) & ~(size_t)255;
    return p;
  };
  u64*   epk    = (u64*)alloc((size_t)NE * 8);
  int*   rp     = (int*)alloc((size_t)(NN + 1) * 4);
  int*   bcount = (int*)alloc((size_t)NBUCK * 4);
  int*   bbase  = (int*)alloc((size_t)(NBUCK + 1) * 4);
  int*   gcur   = (int*)alloc((size_t)NBUCK * 4);
  float* Bmat   = (float*)alloc((size_t)2 * DD * DD * 4);
  float* bias   = (float*)alloc(DD * 4);

  hipLaunchKernelGGL(k_zero_small, dim3(2), dim3(256), 0, stream, bcount, NBUCK);
  hipLaunchKernelGGL(k_bhist, dim3(256), dim3(256), 0, stream, erow, bcount);
  hipLaunchKernelGGL(k_bscan, dim3(1), dim3(512), 0, stream, bcount, bbase, gcur);
  hipLaunchKernelGGL(k_bin, dim3((NE + P1_EDGES - 1) / P1_EDGES), dim3(256), 0, stream,
                     erow, ecol, eval, gcur, epk);
  hipLaunchKernelGGL(k_bsort, dim3(NBUCK), dim3(256), 0, stream, bbase, epk, rp);
  hipLaunchKernelGGL(k_transW, dim3(128), dim3(256), 0, stream, Wp, Ws, bp, bs, Bmat, bias);
  hipLaunchKernelGGL(k_spmm, dim3(NN / 4), dim3(256), 0, stream, rp, epk, X, out);
  hipLaunchKernelGGL(k_gemm, dim3((NN + 63) / 64), dim3(256), 0, stream, out, X, Bmat, bias, out);
}

// Round 3
// 270.130 us; speedup vs baseline: 2.6970x; 1.5725x over previous
//
#include <hip/hip_runtime.h>

#define NN 100000
#define NE 3200000
#define NBUCK 391        // ceil(NN / 256) row-buckets of 256 rows
#define P1_EDGES 12288   // edges per k_bin block
#define P2_CAP 12288     // LDS staging capacity in k_bsort (avg bucket = 8192)

typedef float f4 __attribute__((ext_vector_type(4)));
typedef short bf8 __attribute__((ext_vector_type(8)));   // 8 bf16 = 4 VGPRs (MFMA A/B frag)
typedef unsigned long long u64;

// round-to-nearest-even f32 -> bf16 (as u16 in low bits)
static __device__ __forceinline__ unsigned f2bf(float f) {
  unsigned u = __float_as_uint(f);
  return (u + 0x7FFFu + ((u >> 16) & 1u)) >> 16;
}

// ---------------- bucket histogram (LDS-aggregated) ----------------

__global__ void k_zero_small(int* __restrict__ p, int n) {
  int i = blockIdx.x * 256 + threadIdx.x;
  if (i < n) p[i] = 0;
}

__global__ __launch_bounds__(256) void k_bhist(const int* __restrict__ erow,
                                               int* __restrict__ bcount) {
  __shared__ int cnt[NBUCK];
  for (int i = threadIdx.x; i < NBUCK; i += 256) cnt[i] = 0;
  __syncthreads();
  const long long tid = (long long)blockIdx.x * 256 + threadIdx.x;
  const long long stride = (long long)gridDim.x * 256;
  for (long long e = tid; e < NE; e += stride) atomicAdd(&cnt[erow[e] >> 8], 1);
  __syncthreads();
  for (int i = threadIdx.x; i < NBUCK; i += 256)
    if (cnt[i]) atomicAdd(&bcount[i], cnt[i]);
}

__global__ __launch_bounds__(512) void k_bscan(const int* __restrict__ bcount,
                                               int* __restrict__ bbase,
                                               int* __restrict__ gcur) {
  __shared__ int sh[512];
  const int t = threadIdx.x;
  int v = (t < NBUCK) ? bcount[t] : 0;
  sh[t] = v;
  __syncthreads();
  for (int off = 1; off < 512; off <<= 1) {
    int x = (t >= off) ? sh[t - off] : 0;
    __syncthreads();
    sh[t] += x;
    __syncthreads();
  }
  int excl = (t > 0) ? sh[t - 1] : 0;
  if (t < NBUCK) { bbase[t] = excl; gcur[t] = excl; }
  if (t == NBUCK) bbase[t] = excl;  // == NE
}

// ---------------- pass 1: bin edges into bucket-grouped packed array ----------------
// packed u64: [ rowlocal(8b) << 52 | col(17b) << 32 | f32 val bits ]

__global__ __launch_bounds__(256) void k_bin(const int* __restrict__ erow,
                                             const int* __restrict__ ecol,
                                             const float* __restrict__ eval,
                                             int* __restrict__ gcur,
                                             u64* __restrict__ epk) {
  __shared__ int cnt[NBUCK];
  __shared__ int gbase[NBUCK];
  const int t = threadIdx.x;
  const long long e0 = (long long)blockIdx.x * P1_EDGES;
  long long rem = (long long)NE - e0;
  const int ecnt = (int)(rem < P1_EDGES ? rem : P1_EDGES);
  for (int i = t; i < NBUCK; i += 256) cnt[i] = 0;
  __syncthreads();
  for (int i = t; i < ecnt; i += 256) atomicAdd(&cnt[erow[e0 + i] >> 8], 1);
  __syncthreads();
  for (int i = t; i < NBUCK; i += 256) {
    int c = cnt[i];
    gbase[i] = c ? atomicAdd(&gcur[i], c) : 0;
    cnt[i] = 0;  // reuse as local cursor
  }
  __syncthreads();
  for (int i = t; i < ecnt; i += 256) {
    int r = erow[e0 + i];
    unsigned c = (unsigned)ecol[e0 + i];
    unsigned v = __float_as_uint(eval[e0 + i]);
    int b = r >> 8;
    int p = atomicAdd(&cnt[b], 1);
    u64 pk = ((u64)((((unsigned)(r & 255)) << 20) | c) << 32) | v;
    epk[(long long)gbase[b] + p] = pk;
  }
}

// ---------------- pass 2: per-bucket counting sort (in place) + emit rp ----------------

__global__ __launch_bounds__(256) void k_bsort(const int* __restrict__ bbase,
                                               u64* __restrict__ epk,
                                               int* __restrict__ rp) {
  __shared__ u64 stg[P2_CAP];
  __shared__ int sc[256];
  __shared__ int cur[256];
  const int t = threadIdx.x;
  const int gb = blockIdx.x;
  const int r0 = gb << 8;
  const int rows = (NN - r0 < 256) ? (NN - r0) : 256;
  const int s = bbase[gb];
  const int cnt = bbase[gb + 1] - s;

  cur[t] = 0;
  __syncthreads();
  for (int i = t; i < cnt; i += 256) {
    int rl = (int)((epk[s + i] >> 52) & 255);
    atomicAdd(&cur[rl], 1);
  }
  __syncthreads();
  int c0 = cur[t];
  sc[t] = c0;
  __syncthreads();
  for (int off = 1; off < 256; off <<= 1) {
    int x = (t >= off) ? sc[t - off] : 0;
    __syncthreads();
    sc[t] += x;
    __syncthreads();
  }
  int mybase = sc[t] - c0;  // exclusive scan
  cur[t] = mybase;
  if (t < rows) rp[r0 + t] = s + mybase;
  if (gb == NBUCK - 1 && t == 0) rp[NN] = NE;
  __syncthreads();
  for (int i = t; i < cnt; i += 256) {
    u64 pk = epk[s + i];
    int rl = (int)((pk >> 52) & 255);
    int p = atomicAdd(&cur[rl], 1);
    if (p < P2_CAP) stg[p] = pk;
  }
  __syncthreads();
  for (int i = t; i < cnt; i += 256) epk[s + i] = stg[i];
}

// ---------------- X -> bf16 into d_out row halves: row i bytes [512i, 512i+256) ----------------

__global__ __launch_bounds__(256) void k_xcast(const float* __restrict__ X,
                                               char* __restrict__ ob) {
  int idx = blockIdx.x * 256 + threadIdx.x;   // NN*16 chunks of 8 elems
  if (idx >= NN * 16) return;
  int i = idx >> 4, c = idx & 15;
  const float* xp = X + (size_t)i * 128 + c * 8;
  f4 x0 = *(const f4*)xp;
  f4 x1 = *(const f4*)(xp + 4);
  uint4 o;
  o.x = f2bf(x0[0]) | (f2bf(x0[1]) << 16);
  o.y = f2bf(x0[2]) | (f2bf(x0[3]) << 16);
  o.z = f2bf(x1[0]) | (f2bf(x1[1]) << 16);
  o.w = f2bf(x1[2]) | (f2bf(x1[3]) << 16);
  *(uint4*)(ob + (size_t)i * 512 + c * 16) = o;
}

// ---------------- pack B = [Wp^T ; Ws^T] (K=256 x N=128) into MFMA fragment order ----------------
// frag fid = kbi*8 + ci; lane l, elem b: k = kbi*32 + (l>>4)*8 + b, n = ci*16 + (l&15)

__global__ void k_packB(const float* __restrict__ Wp, const float* __restrict__ Ws,
                        const float* __restrict__ bp, const float* __restrict__ bs,
                        short* __restrict__ Bfrag, float* __restrict__ bias) {
  int idx = blockIdx.x * 256 + threadIdx.x;   // 64 frags * 64 lanes
  if (idx < 64 * 64) {
    int fid = idx >> 6, l = idx & 63;
    int kbi = fid >> 3, ci = fid & 7;
    int n = ci * 16 + (l & 15);
    short v[8];
#pragma unroll
    for (int b = 0; b < 8; b++) {
      int k = kbi * 32 + ((l >> 4) << 3) + b;
      float f = (k < 128) ? Wp[n * 128 + k] : Ws[n * 128 + (k - 128)];
      v[b] = (short)f2bf(f);
    }
    bf8 pk;
#pragma unroll
    for (int b = 0; b < 8; b++) pk[b] = v[b];
    *(bf8*)(Bfrag + (size_t)idx * 8) = pk;
  }
  if (idx < 128) bias[idx] = bp[idx] + bs[idx];
}

// ---------------- SpMM: wave per node, bf16 gather, bf16 agg into d_out row halves ----------------

__global__ __launch_bounds__(256) void k_spmm(const int* __restrict__ rp,
                                              const u64* __restrict__ epk,
                                              char* __restrict__ ob) {
  const int w = threadIdx.x >> 6;
  const int lane = threadIdx.x & 63;
  const int node = blockIdx.x * 4 + w;
  int beg = __builtin_amdgcn_readfirstlane(rp[node]);
  int end = __builtin_amdgcn_readfirstlane(rp[node + 1]);
  const int lb = lane * 4;
  float ax = 0.f, ay = 0.f;
  int e = beg;
  for (; e + 4 <= end; e += 4) {
    u64 p0 = epk[e], p1 = epk[e + 1], p2 = epk[e + 2], p3 = epk[e + 3];
    int c0 = (int)(p0 >> 32) & 0x1FFFF; float v0 = __uint_as_float((unsigned)p0);
    int c1 = (int)(p1 >> 32) & 0x1FFFF; float v1 = __uint_as_float((unsigned)p1);
    int c2 = (int)(p2 >> 32) & 0x1FFFF; float v2 = __uint_as_float((unsigned)p2);
    int c3 = (int)(p3 >> 32) & 0x1FFFF; float v3 = __uint_as_float((unsigned)p3);
    unsigned x0 = *(const unsigned*)(ob + (size_t)c0 * 512 + lb);
    unsigned x1 = *(const unsigned*)(ob + (size_t)c1 * 512 + lb);
    unsigned x2 = *(const unsigned*)(ob + (size_t)c2 * 512 + lb);
    unsigned x3 = *(const unsigned*)(ob + (size_t)c3 * 512 + lb);
    ax += v0 * __uint_as_float(x0 << 16); ay += v0 * __uint_as_float(x0 & 0xFFFF0000u);
    ax += v1 * __uint_as_float(x1 << 16); ay += v1 * __uint_as_float(x1 & 0xFFFF0000u);
    ax += v2 * __uint_as_float(x2 << 16); ay += v2 * __uint_as_float(x2 & 0xFFFF0000u);
    ax += v3 * __uint_as_float(x3 << 16); ay += v3 * __uint_as_float(x3 & 0xFFFF0000u);
  }
  for (; e < end; e++) {
    u64 p0 = epk[e];
    int c = (int)(p0 >> 32) & 0x1FFFF; float v = __uint_as_float((unsigned)p0);
    unsigned x = *(const unsigned*)(ob + (size_t)c * 512 + lb);
    ax += v * __uint_as_float(x << 16); ay += v * __uint_as_float(x & 0xFFFF0000u);
  }
  unsigned o = f2bf(ax) | (f2bf(ay) << 16);
  *(unsigned*)(ob + (size_t)node * 512 + 256 + lb) = o;
}

// ---------------- MFMA GEMM: out = [agg|X]_bf16 @ B + bias   (M=100k, K=256, N=128) ----------------
// A rows live interleaved in d_out: row i = [Xh 256B | aggH 256B]; block reads only
// its own 128 rows during K loop, then overwrites exactly those rows -> safe.

__global__ __launch_bounds__(256) void k_gemm(const char* __restrict__ ab,
                                              const short* __restrict__ Bfrag,
                                              const float* __restrict__ bias,
                                              float* __restrict__ out) {
  const int t = threadIdx.x;
  const int w = t >> 6, l = t & 63;
  const int i0 = blockIdx.x * 128 + w * 32;
  const int lm = l & 15, lk = l >> 4;

  f4 acc[2][8];
#pragma unroll
  for (int mi = 0; mi < 2; mi++)
#pragma unroll
    for (int ci = 0; ci < 8; ci++) acc[mi][ci] = (f4){0.f, 0.f, 0.f, 0.f};

  int r0 = i0 + lm;       if (r0 > NN - 1) r0 = NN - 1;
  int r1 = i0 + 16 + lm;  if (r1 > NN - 1) r1 = NN - 1;
  const bf8* __restrict__ bfp = (const bf8*)Bfrag;

#pragma unroll
  for (int kb = 0; kb < 8; kb++) {
    // kb 0..3: aggH (k 0..127, Wp rows); kb 4..7: Xh (k 128..255, Ws rows)
    const int off = (kb < 4) ? (256 + kb * 64) : ((kb - 4) * 64);
    bf8 a0 = *(const bf8*)(ab + (size_t)r0 * 512 + off + lk * 16);
    bf8 a1 = *(const bf8*)(ab + (size_t)r1 * 512 + off + lk * 16);
#pragma unroll
    for (int ci = 0; ci < 8; ci++) {
      bf8 b = bfp[(size_t)(kb * 8 + ci) * 64 + l];
      acc[0][ci] = __builtin_amdgcn_mfma_f32_16x16x32_bf16(a0, b, acc[0][ci], 0, 0, 0);
      acc[1][ci] = __builtin_amdgcn_mfma_f32_16x16x32_bf16(a1, b, acc[1][ci], 0, 0, 0);
    }
  }

#pragma unroll
  for (int ci = 0; ci < 8; ci++) {
    int col = ci * 16 + lm;
    float bv = bias[col];
#pragma unroll
    for (int mi = 0; mi < 2; mi++) {
      int rbase = i0 + mi * 16 + lk * 4;
#pragma unroll
      for (int r = 0; r < 4; r++) {
        int row = rbase + r;
        if (row < NN) out[(size_t)row * 128 + col] = acc[mi][ci][r] + bv;
      }
    }
  }
}

// ---------------- launch ----------------

extern "C" void kernel_launch(void* const* d_in, const int* in_sizes, int n_in,
                              void* d_out, int out_size, void* d_ws, size_t ws_size,
                              hipStream_t stream) {
  (void)in_sizes; (void)n_in; (void)out_size; (void)ws_size;
  const int*   erow = (const int*)d_in[0];
  const int*   ecol = (const int*)d_in[1];
  const float* eval = (const float*)d_in[2];
  const float* X    = (const float*)d_in[3];
  const float* Wp   = (const float*)d_in[4];
  const float* bp   = (const float*)d_in[5];
  const float* Ws   = (const float*)d_in[6];
  const float* bs   = (const float*)d_in[7];
  float* out = (float*)d_out;

  char* ws = (char*)d_ws;
  size_t off = 0;
  auto alloc = [&](size_t bytes) -> void* {
    void* p = ws + off;
    off = (off + bytes + 255) & ~(size_t)255;
    return p;
  };
  u64*   epk    = (u64*)alloc((size_t)NE * 8);
  int*   rp     = (int*)alloc((size_t)(NN + 1) * 4);
  int*   bcount = (int*)alloc((size_t)NBUCK * 4);
  int*   bbase  = (int*)alloc((size_t)(NBUCK + 1) * 4);
  int*   gcur   = (int*)alloc((size_t)NBUCK * 4);
  short* Bfrag  = (short*)alloc((size_t)64 * 64 * 8 * 2);
  float* bias   = (float*)alloc(128 * 4);

  hipLaunchKernelGGL(k_zero_small, dim3(2), dim3(256), 0, stream, bcount, NBUCK);
  hipLaunchKernelGGL(k_bhist, dim3(256), dim3(256), 0, stream, erow, bcount);
  hipLaunchKernelGGL(k_bscan, dim3(1), dim3(512), 0, stream, bcount, bbase, gcur);
  hipLaunchKernelGGL(k_bin, dim3((NE + P1_EDGES - 1) / P1_EDGES), dim3(256), 0, stream,
                     erow, ecol, eval, gcur, epk);
  hipLaunchKernelGGL(k_bsort, dim3(NBUCK), dim3(256), 0, stream, bbase, epk, rp);
  hipLaunchKernelGGL(k_packB, dim3(16), dim3(256), 0, stream, Wp, Ws, bp, bs, Bfrag, bias);
  hipLaunchKernelGGL(k_xcast, dim3((NN * 16 + 255) / 256), dim3(256), 0, stream, X, (char*)d_out);
  hipLaunchKernelGGL(k_spmm, dim3(NN / 4), dim3(256), 0, stream, rp, epk, (char*)d_out);
  hipLaunchKernelGGL(k_gemm, dim3((NN + 127) / 128), dim3(256), 0, stream,
                     (const char*)d_out, Bfrag, bias, out);
}